// Round 5
// baseline (2250.837 us; speedup 1.0000x reference)
//
#include <hip/hip_runtime.h>
#include <cstdint>
#include <cstddef>

#define B_ROWS 16384
#define EMB_LEN 16384
#define K_DIM 128
#define JSPLIT 8
#define JLEN (EMB_LEN / JSPLIT)   // 2048
#define RB 32                     // rows per block
#define JT 256                    // j-tile (4 j per lane — R0's proven width)
#define KC 16                     // k chunk

typedef const __attribute__((address_space(1))) void* gas_vp;
typedef __attribute__((address_space(3))) void* las_vp;

__device__ __forceinline__ void dma16(const float* g, float* l) {
    // global -> LDS direct copy, 16 B/lane; LDS dest = wave-uniform base + lane*16
    __builtin_amdgcn_global_load_lds((gas_vp)g, (las_vp)l, 16, 0, 0);
}

// wave-uniform float -> SGPR (bit-identical value)
__device__ __forceinline__ float rfl(float x) {
    return __int_as_float(__builtin_amdgcn_readfirstlane(__float_as_int(x)));
}

// ---------------------------------------------------------------------------
// Kernel 1: zf + C per row.  (frozen — absmax 0 throughout)
// ---------------------------------------------------------------------------
__global__ void zf_kernel(const float* __restrict__ z,
                          float* __restrict__ zf, float* __restrict__ Cb) {
    int b = blockIdx.x;
    int i = threadIdx.x;                 // 0..127
    int c = i >> 3, h = (i >> 1) & 1, wp = i & 1;
    const float* zr = z + (size_t)b * 128 + c * 8 + h * 4 + wp * 2;
    float v = 0.5f * zr[0] + 0.5f * zr[1];
    zf[(size_t)b * 128 + i] = v;
    float s = v * v;
    for (int o = 32; o; o >>= 1) s += __shfl_down(s, o, 64);
    __shared__ float sm[2];
    if ((threadIdx.x & 63) == 0) sm[threadIdx.x >> 6] = s;
    __syncthreads();
    if (threadIdx.x == 0) Cb[b] = sm[0] + sm[1];
}

// ---------------------------------------------------------------------------
// Kernel 1b: embT[k][j] = emb[j][k]  (frozen — verified R4+)
// ---------------------------------------------------------------------------
__global__ void transpose_kernel(const float* __restrict__ emb,
                                 float* __restrict__ embT) {
    __shared__ float t[128][65];   // [k][j-local], +1 pad
    int j0 = blockIdx.x * 64;
    int jl = threadIdx.x >> 2;         // 0..63
    int kq = threadIdx.x & 3;          // 0..3
    const float* er = emb + (size_t)(j0 + jl) * 128;
#pragma unroll
    for (int q = 0; q < 8; ++q) {
        int k4 = (kq * 8 + q) * 4;
        float4 v = *(const float4*)(er + k4);
        t[k4 + 0][jl] = v.x;
        t[k4 + 1][jl] = v.y;
        t[k4 + 2][jl] = v.z;
        t[k4 + 3][jl] = v.w;
    }
    __syncthreads();
    int kk = threadIdx.x >> 4;         // 0..15
    int jl4 = (threadIdx.x & 15) * 4;
#pragma unroll
    for (int q = 0; q < 8; ++q) {
        int k = kk + q * 16;
        float4 v = make_float4(t[k][jl4], t[k][jl4 + 1], t[k][jl4 + 2], t[k][jl4 + 3]);
        *(float4*)(embT + (size_t)k * EMB_LEN + j0 + jl4) = v;
    }
}

// ---------------------------------------------------------------------------
// Kernel 2: argmin of d = C - 2*dot(zf, e_j).
// R10 = R0's proven 4-wide skeleton (JT=256, KC=16, double-buffered DMA,
// named bd/bj, VGPR~60, NO spill) with the a-operand moved OFF the LDS pipe:
//   - zfs LDS tile DELETED.  a-values come straight from zf global via
//     wave-uniform addresses (readfirstlane'd row index -> SMEM s_load into
//     SGPRs; rfl() on the value pins SGPR).  v_fma_f32 takes 1 SGPR operand.
//   - per k-step the wave now issues 1 ds_read_b128 (bv) instead of 3
//     -> CU LDS-pipe demand 2.25x oversubscribed -> 0.75x (under).
//   - LDS = es only (32 KB) -> 4 blocks/CU (occupancy 31% -> ~50%).
// R8/R9 POST-MORTEM: launch_bounds/waves_per_eu were IGNORED by the
// allocator (VGPR stuck at 84, bd/bj spilled -> 1.2-1.8 GB scratch traffic).
// Rule: stay under the known-safe register envelope instead of fighting
// the allocator.  Demand here is BELOW R0's (a0/a1 + zfs staging gone).
// Arithmetic contract (frozen, absmax 0 throughout): per (r,j) single fp32
// FMA chain ascending k (a-values bit-identical: same zf floats, different
// path); d = C - 2g; strict < argmin ascending j; lexicographic (d,j) wave
// reduce; splits ascending.
// ---------------------------------------------------------------------------
#define FMA_ROW(cr, av) \
    cr.x = fmaf(av, bv.x, cr.x); \
    cr.y = fmaf(av, bv.y, cr.y); \
    cr.z = fmaf(av, bv.z, cr.z); \
    cr.w = fmaf(av, bv.w, cr.w);

// ascending-j strict-< running chain (earliest j wins ties == lexicographic min)
#define UPD(rr, cr) { \
    float dv0 = cb##rr - 2.0f * cr.x; \
    float dv1 = cb##rr - 2.0f * cr.y; \
    float dv2 = cb##rr - 2.0f * cr.z; \
    float dv3 = cb##rr - 2.0f * cr.w; \
    if (dv0 < bd##rr) { bd##rr = dv0; bj##rr = jb; } \
    if (dv1 < bd##rr) { bd##rr = dv1; bj##rr = jb + 1; } \
    if (dv2 < bd##rr) { bd##rr = dv2; bj##rr = jb + 2; } \
    if (dv3 < bd##rr) { bd##rr = dv3; bj##rr = jb + 3; } \
}

#define RED(rr) { \
    float bd = bd##rr; int bj = bj##rr; \
    for (int o = 32; o; o >>= 1) { \
        float d2 = __shfl_down(bd, o, 64); \
        int j2 = __shfl_down(bj, o, 64); \
        if (d2 < bd || (d2 == bd && j2 < bj)) { bd = d2; bj = j2; } \
    } \
    if (l == 0) { \
        cand_d[sp * B_ROWS + rbase + w8 + rr] = bd; \
        cand_j[sp * B_ROWS + rbase + w8 + rr] = bj; \
    } \
}

__global__ void argmin_kernel(const float* __restrict__ zf,
                              const float* __restrict__ Cb,
                              const float* __restrict__ embT,
                              float* __restrict__ cand_d,
                              int* __restrict__ cand_j) {
    __shared__ float es[2][KC][JT];    // double-buffered staged chunk, 32 KB (only LDS)

    int sp = blockIdx.x & 7;           // XCD id under round-robin dispatch
    int rb = blockIdx.x >> 3;          // 0..511
    int rbase = rb * RB;
    int jbase = sp * JLEN;
    int tid = threadIdx.x;
    int w = tid >> 6;                  // wave 0..3
    int l = tid & 63;
    int w8 = w << 3;
    int l4 = l << 2;

    // wave-uniform row base, pinned uniform for SMEM scalar loads
    int rbu = __builtin_amdgcn_readfirstlane(rbase + w8);
    const float* zp0 = zf + (size_t)rbu * K_DIM;
    const float* zp1 = zp0 + K_DIM;
    const float* zp2 = zp0 + 2 * K_DIM;
    const float* zp3 = zp0 + 3 * K_DIM;
    const float* zp4 = zp0 + 4 * K_DIM;
    const float* zp5 = zp0 + 5 * K_DIM;
    const float* zp6 = zp0 + 6 * K_DIM;
    const float* zp7 = zp0 + 7 * K_DIM;

    // row constants — wave-uniform, in SGPRs
    const float* cbp = Cb + rbu;
    float cb0 = rfl(cbp[0]), cb1 = rfl(cbp[1]), cb2 = rfl(cbp[2]), cb3 = rfl(cbp[3]);
    float cb4 = rfl(cbp[4]), cb5 = rfl(cbp[5]), cb6 = rfl(cbp[6]), cb7 = rfl(cbp[7]);

    // per-lane running best (named scalars)
    float bd0 = 3.4e38f, bd1 = 3.4e38f, bd2 = 3.4e38f, bd3 = 3.4e38f;
    float bd4 = 3.4e38f, bd5 = 3.4e38f, bd6 = 3.4e38f, bd7 = 3.4e38f;
    int bj0 = 0, bj1 = 0, bj2 = 0, bj3 = 0, bj4 = 0, bj5 = 0, bj6 = 0, bj7 = 0;

    // prologue DMA: stage (jt=0, kc=0) into buffer 0
    {
        const float* gb = embT + jbase + l4;
        float* lb = &es[0][w][0];
        dma16(gb + (size_t)(0 + w) * EMB_LEN, lb + 0 * JT);
        dma16(gb + (size_t)(4 + w) * EMB_LEN, lb + 4 * JT);
        dma16(gb + (size_t)(8 + w) * EMB_LEN, lb + 8 * JT);
        dma16(gb + (size_t)(12 + w) * EMB_LEN, lb + 12 * JT);
    }

    int buf = 0;
    for (int jt = 0; jt < JLEN; jt += JT) {
        float4 c0 = make_float4(0.f, 0.f, 0.f, 0.f);
        float4 c1 = make_float4(0.f, 0.f, 0.f, 0.f);
        float4 c2 = make_float4(0.f, 0.f, 0.f, 0.f);
        float4 c3 = make_float4(0.f, 0.f, 0.f, 0.f);
        float4 c4 = make_float4(0.f, 0.f, 0.f, 0.f);
        float4 c5 = make_float4(0.f, 0.f, 0.f, 0.f);
        float4 c6 = make_float4(0.f, 0.f, 0.f, 0.f);
        float4 c7 = make_float4(0.f, 0.f, 0.f, 0.f);

        for (int kc = 0; kc < K_DIM; kc += KC) {
            // Drains the DMA for (jt,kc) — in flight for a full chunk-compute —
            // and guarantees everyone is done reading the other buffer.
            __syncthreads();

            // issue next-stage DMA into the other buffer (hidden under compute)
            {
                int kc2 = kc + KC, jt2 = jt;
                if (kc2 == K_DIM) { kc2 = 0; jt2 += JT; }
                if (jt2 < JLEN) {
                    const float* gb = embT + (size_t)kc2 * EMB_LEN + jbase + jt2 + l4;
                    float* lb = &es[buf ^ 1][w][0];
                    dma16(gb + (size_t)(0 + w) * EMB_LEN, lb + 0 * JT);
                    dma16(gb + (size_t)(4 + w) * EMB_LEN, lb + 4 * JT);
                    dma16(gb + (size_t)(8 + w) * EMB_LEN, lb + 8 * JT);
                    dma16(gb + (size_t)(12 + w) * EMB_LEN, lb + 12 * JT);
                }
            }

            const float (*eb)[JT] = es[buf];
#pragma unroll
            for (int k = 0; k < KC; ++k) {
                const float4 bv = *(const float4*)(&eb[k][l4]);   // only LDS read
                int kk = kc + k;
                // a-operand: wave-uniform scalar loads -> SGPR (bit-identical zf floats)
                float a0 = rfl(zp0[kk]);
                float a1 = rfl(zp1[kk]);
                float a2 = rfl(zp2[kk]);
                float a3 = rfl(zp3[kk]);
                float a4 = rfl(zp4[kk]);
                float a5 = rfl(zp5[kk]);
                float a6 = rfl(zp6[kk]);
                float a7 = rfl(zp7[kk]);
                FMA_ROW(c0, a0)
                FMA_ROW(c1, a1)
                FMA_ROW(c2, a2)
                FMA_ROW(c3, a3)
                FMA_ROW(c4, a4)
                FMA_ROW(c5, a5)
                FMA_ROW(c6, a6)
                FMA_ROW(c7, a7)
            }
            buf ^= 1;
        }

        // per-jt epilogue: d = C - 2g; ascending-j strict-< running best
        int jb = jbase + jt + l4;
        UPD(0, c0)
        UPD(1, c1)
        UPD(2, c2)
        UPD(3, c3)
        UPD(4, c4)
        UPD(5, c5)
        UPD(6, c6)
        UPD(7, c7)
    }

    // final cross-lane lexicographic (d,j) reduce per row; lane 0 writes
    RED(0)
    RED(1)
    RED(2)
    RED(3)
    RED(4)
    RED(5)
    RED(6)
    RED(7)
}

// ---------------------------------------------------------------------------
// Kernel 3: merge splits (ascending split + strict < => smallest j wins ties)
// ---------------------------------------------------------------------------
__global__ void merge_kernel(const float* __restrict__ cand_d,
                             const int* __restrict__ cand_j,
                             int* __restrict__ idxw,
                             float* __restrict__ out_idx) {
    int b = blockIdx.x * 256 + threadIdx.x;
    float bd = cand_d[b];
    int bj = cand_j[b];
#pragma unroll
    for (int s = 1; s < JSPLIT; ++s) {
        float d = cand_d[s * B_ROWS + b];
        int j = cand_j[s * B_ROWS + b];
        if (d < bd) { bd = d; bj = j; }
    }
    idxw[b] = bj;
    out_idx[b] = (float)bj;
}

// ---------------------------------------------------------------------------
// Kernel 4: z_q_out (transposed) + moment sums for loss
// ---------------------------------------------------------------------------
__global__ void output_kernel(const float* __restrict__ z,
                              const float* __restrict__ emb,
                              const int* __restrict__ idxw,
                              float* __restrict__ out,
                              double* __restrict__ accs) {
    int stride = gridDim.x * blockDim.x;
    double s[6] = {0, 0, 0, 0, 0, 0};
    for (int n = blockIdx.x * blockDim.x + threadIdx.x; n < B_ROWS * 128; n += stride) {
        int b = n >> 7, i = n & 127;
        int c = i >> 3, h = (i >> 2) & 1, w = i & 3;   // i = c*8 + h*4 + w
        float zv = z[n];
        float qv = emb[(size_t)idxw[b] * 128 + i];
        float diff = qv - zv;                          // z_q - z (fp32, as ref)
        out[(size_t)((b * 4 + w) * 16 + c) * 2 + h] = zv + diff;
        s[0] += (double)qv;
        s[1] += (double)zv;
        s[2] += (double)qv * qv;
        s[3] += (double)zv * zv;
        s[4] += (double)qv * zv;
        s[5] += (double)diff * diff;
    }
    int lane = threadIdx.x & 63, wv = threadIdx.x >> 6;
#pragma unroll
    for (int q = 0; q < 6; ++q)
        for (int o = 32; o; o >>= 1) s[q] += __shfl_down(s[q], o, 64);
    __shared__ double sm[6][4];
    if (lane == 0)
#pragma unroll
        for (int q = 0; q < 6; ++q) sm[q][wv] = s[q];
    __syncthreads();
    if (threadIdx.x == 0) {
#pragma unroll
        for (int q = 0; q < 6; ++q)
            atomicAdd(&accs[q], sm[q][0] + sm[q][1] + sm[q][2] + sm[q][3]);
    }
}

// ---------------------------------------------------------------------------
// Kernel 5: per-column L1 of emb (for reg term)
// ---------------------------------------------------------------------------
__global__ void colsum_kernel(const float* __restrict__ emb, float* __restrict__ colsum) {
    int j = blockIdx.x;   // 0..127
    double s = 0;
    for (int i = threadIdx.x; i < EMB_LEN; i += blockDim.x)
        s += (double)fabsf(emb[(size_t)i * 128 + j]);
    int lane = threadIdx.x & 63, wv = threadIdx.x >> 6;
    for (int o = 32; o; o >>= 1) s += __shfl_down(s, o, 64);
    __shared__ double sm[4];
    if (lane == 0) sm[wv] = s;
    __syncthreads();
    if (threadIdx.x == 0) colsum[j] = (float)(sm[0] + sm[1] + sm[2] + sm[3]);
}

// ---------------------------------------------------------------------------
// Kernel 6: final loss
// ---------------------------------------------------------------------------
__global__ void loss_kernel(const double* __restrict__ accs,
                            const float* __restrict__ colsum,
                            float* __restrict__ out_loss) {
    __shared__ float sm[128];
    int tid = threadIdx.x;
    sm[tid] = colsum[tid];
    __syncthreads();
    for (int s = 64; s; s >>= 1) {
        if (tid < s) sm[tid] = fmaxf(sm[tid], sm[tid + s]);
        __syncthreads();
    }
    if (tid == 0) {
        double n = (double)B_ROWS * 128.0;
        double m = accs[5] / n;                   // mean((z_q - z)^2)
        double commit = 0.25 * m + m;
        double Sx = accs[0], Sy = accs[1], Sxx = accs[2], Syy = accs[3], Sxy = accs[4];
        double cov = Sxy - Sx * Sy / n;
        double vx = Sxx - Sx * Sx / n;
        double vy = Syy - Sy * Sy / n;
        double pearson = 0.5 + 0.5 * cov / (sqrt(vx) * sqrt(vy));
        double reg = 0.01 * (double)sm[0];
        out_loss[0] = (float)(commit + pearson + reg);
    }
}

// ---------------------------------------------------------------------------
extern "C" void kernel_launch(void* const* d_in, const int* in_sizes, int n_in,
                              void* d_out, int out_size, void* d_ws, size_t ws_size,
                              hipStream_t stream) {
    const float* z = (const float*)d_in[0];      // 16384*16*2*4
    const float* emb = (const float*)d_in[1];    // 16384*128
    float* out = (float*)d_out;                  // 2097152 (z_q_out) + 1 (loss) + 16384 (idx)

    float* zf = (float*)d_ws;                    // 2097152 floats
    float* embT = zf + 2097152;                  // 2097152 floats (emb transposed)
    float* Cb = embT + 2097152;                  // 16384
    float* cand_d = Cb + 16384;                  // JSPLIT*16384
    int* cand_j = (int*)(cand_d + JSPLIT * B_ROWS);
    int* idxw = cand_j + JSPLIT * B_ROWS;        // 16384
    double* accs = (double*)(idxw + 16384);      // 8 doubles
    float* colsum = (float*)(accs + 8);          // 128

    hipMemsetAsync(accs, 0, 8 * sizeof(double), stream);

    zf_kernel<<<B_ROWS, 128, 0, stream>>>(z, zf, Cb);
    transpose_kernel<<<EMB_LEN / 64, 256, 0, stream>>>(emb, embT);
    argmin_kernel<<<512 * JSPLIT, 256, 0, stream>>>(zf, Cb, embT, cand_d, cand_j);
    merge_kernel<<<B_ROWS / 256, 256, 0, stream>>>(cand_d, cand_j, idxw, out + 2097153);
    output_kernel<<<1024, 256, 0, stream>>>(z, emb, idxw, out, accs);
    colsum_kernel<<<128, 256, 0, stream>>>(emb, colsum);
    loss_kernel<<<1, 128, 0, stream>>>(accs, colsum, out + 2097152);
}

// Round 7
// 911.909 us; speedup vs baseline: 2.4683x; 2.4683x over previous
//
#include <hip/hip_runtime.h>
#include <cstdint>
#include <cstddef>

#define B_ROWS 16384
#define EMB_LEN 16384
#define K_DIM 128
#define JSPLIT 8
#define JLEN (EMB_LEN / JSPLIT)   // 2048
#define RB 32                     // rows per block
#define JT 256                    // j-tile (4 j per lane — proven width)
#define KC 16                     // k chunk

typedef const __attribute__((address_space(1))) void* gas_vp;
typedef __attribute__((address_space(3))) void* las_vp;
typedef __attribute__((ext_vector_type(4))) unsigned int u32x4;

__device__ __forceinline__ void dma16(const float* g, float* l) {
    // global -> LDS direct copy, 16 B/lane; LDS dest = wave-uniform base + lane*16
    __builtin_amdgcn_global_load_lds((gas_vp)g, (las_vp)l, 16, 0, 0);
}

// wave-uniform float -> SGPR (bit-identical value)
__device__ __forceinline__ float rfl(float x) {
    return __int_as_float(__builtin_amdgcn_readfirstlane(__float_as_int(x)));
}

// ---------------------------------------------------------------------------
// Kernel 1: zf + C per row.  (frozen — absmax 0 throughout)
// ---------------------------------------------------------------------------
__global__ void zf_kernel(const float* __restrict__ z,
                          float* __restrict__ zf, float* __restrict__ Cb) {
    int b = blockIdx.x;
    int i = threadIdx.x;                 // 0..127
    int c = i >> 3, h = (i >> 1) & 1, wp = i & 1;
    const float* zr = z + (size_t)b * 128 + c * 8 + h * 4 + wp * 2;
    float v = 0.5f * zr[0] + 0.5f * zr[1];
    zf[(size_t)b * 128 + i] = v;
    float s = v * v;
    for (int o = 32; o; o >>= 1) s += __shfl_down(s, o, 64);
    __shared__ float sm[2];
    if ((threadIdx.x & 63) == 0) sm[threadIdx.x >> 6] = s;
    __syncthreads();
    if (threadIdx.x == 0) Cb[b] = sm[0] + sm[1];
}

// ---------------------------------------------------------------------------
// Kernel 1b: embT[k][j] = emb[j][k]  (frozen — verified R4+)
// ---------------------------------------------------------------------------
__global__ void transpose_kernel(const float* __restrict__ emb,
                                 float* __restrict__ embT) {
    __shared__ float t[128][65];   // [k][j-local], +1 pad
    int j0 = blockIdx.x * 64;
    int jl = threadIdx.x >> 2;         // 0..63
    int kq = threadIdx.x & 3;          // 0..3
    const float* er = emb + (size_t)(j0 + jl) * 128;
#pragma unroll
    for (int q = 0; q < 8; ++q) {
        int k4 = (kq * 8 + q) * 4;
        float4 v = *(const float4*)(er + k4);
        t[k4 + 0][jl] = v.x;
        t[k4 + 1][jl] = v.y;
        t[k4 + 2][jl] = v.z;
        t[k4 + 3][jl] = v.w;
    }
    __syncthreads();
    int kk = threadIdx.x >> 4;         // 0..15
    int jl4 = (threadIdx.x & 15) * 4;
#pragma unroll
    for (int q = 0; q < 8; ++q) {
        int k = kk + q * 16;
        float4 v = make_float4(t[k][jl4], t[k][jl4 + 1], t[k][jl4 + 2], t[k][jl4 + 3]);
        *(float4*)(embT + (size_t)k * EMB_LEN + j0 + jl4) = v;
    }
}

// ---------------------------------------------------------------------------
// Kernel 2: argmin of d = C - 2*dot(zf, e_j).
// R12 = R10's verified skeleton (4-wide j, JT=256, KC=16, es-only 32 KB LDS,
// DMA double-buffer, named bd/bj, ~56 VGPR no-spill at DEFAULT allocator
// settings) + a-operand on the SMEM pipe via EXPLICIT inline-asm s_load.
//   R10 POST-MORTEM: rfl(load) lowered to per-lane global_load + readfirstlane
//     -> VALU-instruction-bound (VALUBusy 93%, 2200 us).  Mechanism right,
//     pipe wrong.
//   R11 (addrspace(4) cast) never ran — container failed; the cast is the one
//     novel construct that could ICE hipcc, so this round emits the scalar
//     loads explicitly: per 4-k group, ONE asm block = 8x s_load_dwordx4
//     (8 rows x 4 k, row stride 512 B as literal offsets, one SGPR-pair base)
//     + s_waitcnt lgkmcnt(0) INSIDE the block (consumers data-depend on the
//     asm outputs -> no hoist hazard).  a-values land in SGPRs; v_fma takes
//     1 SGPR operand; __uint_as_float is a free bit-cast.
// Per k-step: 32 FMA + 1 ds_read_b128 -> LDS pipe 0.75x subscribed (was
// 2.25x in R0 = the measured 866/437 = 1.98x slowdown).  SMEM latency hidden
// by ~16-20 waves/CU (zf slice is K$/L2-resident, 16 KB/block).
// Arithmetic contract (frozen, absmax 0 throughout): per (r,j) single fp32
// FMA chain ascending k (identical zf bits, identical order); d = C - 2g;
// strict < argmin ascending j; lexicographic (d,j) wave reduce; splits
// ascending.
// ---------------------------------------------------------------------------
#define FMA_ROW(cr, av) \
    cr.x = fmaf(av, bv.x, cr.x); \
    cr.y = fmaf(av, bv.y, cr.y); \
    cr.z = fmaf(av, bv.z, cr.z); \
    cr.w = fmaf(av, bv.w, cr.w);

// one k-step: bv from LDS (per-lane), a-values from SGPRs (kk is a literal)
#define KSTEP(g, kk) { \
    const float4 bv = *(const float4*)(&eb[(g) * 4 + (kk)][l4]); \
    FMA_ROW(c0, __uint_as_float(A0[kk])) \
    FMA_ROW(c1, __uint_as_float(A1[kk])) \
    FMA_ROW(c2, __uint_as_float(A2[kk])) \
    FMA_ROW(c3, __uint_as_float(A3[kk])) \
    FMA_ROW(c4, __uint_as_float(A4[kk])) \
    FMA_ROW(c5, __uint_as_float(A5[kk])) \
    FMA_ROW(c6, __uint_as_float(A6[kk])) \
    FMA_ROW(c7, __uint_as_float(A7[kk])) \
}

// ascending-j strict-< running chain (earliest j wins ties == lexicographic min)
#define UPD(rr, cr) { \
    float dv0 = cb##rr - 2.0f * cr.x; \
    float dv1 = cb##rr - 2.0f * cr.y; \
    float dv2 = cb##rr - 2.0f * cr.z; \
    float dv3 = cb##rr - 2.0f * cr.w; \
    if (dv0 < bd##rr) { bd##rr = dv0; bj##rr = jb; } \
    if (dv1 < bd##rr) { bd##rr = dv1; bj##rr = jb + 1; } \
    if (dv2 < bd##rr) { bd##rr = dv2; bj##rr = jb + 2; } \
    if (dv3 < bd##rr) { bd##rr = dv3; bj##rr = jb + 3; } \
}

#define RED(rr) { \
    float bd = bd##rr; int bj = bj##rr; \
    for (int o = 32; o; o >>= 1) { \
        float d2 = __shfl_down(bd, o, 64); \
        int j2 = __shfl_down(bj, o, 64); \
        if (d2 < bd || (d2 == bd && j2 < bj)) { bd = d2; bj = j2; } \
    } \
    if (l == 0) { \
        cand_d[sp * B_ROWS + rbase + w8 + rr] = bd; \
        cand_j[sp * B_ROWS + rbase + w8 + rr] = bj; \
    } \
}

__global__ void argmin_kernel(const float* __restrict__ zf,
                              const float* __restrict__ Cb,
                              const float* __restrict__ embT,
                              float* __restrict__ cand_d,
                              int* __restrict__ cand_j) {
    __shared__ float es[2][KC][JT];    // double-buffered staged chunk, 32 KB (only LDS)

    int sp = blockIdx.x & 7;           // XCD id under round-robin dispatch
    int rb = blockIdx.x >> 3;          // 0..511
    int rbase = rb * RB;
    int jbase = sp * JLEN;
    int tid = threadIdx.x;
    int w = tid >> 6;                  // wave 0..3
    int l = tid & 63;
    int w8 = w << 3;
    int l4 = l << 2;

    // wave-uniform row base -> scalar (SGPR) address of this wave's 8 zf rows
    int rbu = __builtin_amdgcn_readfirstlane(rbase + w8);
    unsigned long long zb =
        (unsigned long long)(uintptr_t)zf + (unsigned long long)rbu * (K_DIM * 4);

    // row constants — wave-uniform, pinned to SGPR (proven R10 path)
    const float* cbp = Cb + rbu;
    float cb0 = rfl(cbp[0]), cb1 = rfl(cbp[1]), cb2 = rfl(cbp[2]), cb3 = rfl(cbp[3]);
    float cb4 = rfl(cbp[4]), cb5 = rfl(cbp[5]), cb6 = rfl(cbp[6]), cb7 = rfl(cbp[7]);

    // per-lane running best (named scalars)
    float bd0 = 3.4e38f, bd1 = 3.4e38f, bd2 = 3.4e38f, bd3 = 3.4e38f;
    float bd4 = 3.4e38f, bd5 = 3.4e38f, bd6 = 3.4e38f, bd7 = 3.4e38f;
    int bj0 = 0, bj1 = 0, bj2 = 0, bj3 = 0, bj4 = 0, bj5 = 0, bj6 = 0, bj7 = 0;

    // prologue DMA: stage (jt=0, kc=0) into buffer 0
    {
        const float* gb = embT + jbase + l4;
        float* lb = &es[0][w][0];
        dma16(gb + (size_t)(0 + w) * EMB_LEN, lb + 0 * JT);
        dma16(gb + (size_t)(4 + w) * EMB_LEN, lb + 4 * JT);
        dma16(gb + (size_t)(8 + w) * EMB_LEN, lb + 8 * JT);
        dma16(gb + (size_t)(12 + w) * EMB_LEN, lb + 12 * JT);
    }

    int buf = 0;
    for (int jt = 0; jt < JLEN; jt += JT) {
        float4 c0 = make_float4(0.f, 0.f, 0.f, 0.f);
        float4 c1 = make_float4(0.f, 0.f, 0.f, 0.f);
        float4 c2 = make_float4(0.f, 0.f, 0.f, 0.f);
        float4 c3 = make_float4(0.f, 0.f, 0.f, 0.f);
        float4 c4 = make_float4(0.f, 0.f, 0.f, 0.f);
        float4 c5 = make_float4(0.f, 0.f, 0.f, 0.f);
        float4 c6 = make_float4(0.f, 0.f, 0.f, 0.f);
        float4 c7 = make_float4(0.f, 0.f, 0.f, 0.f);

        for (int kc = 0; kc < K_DIM; kc += KC) {
            // Drains the DMA for (jt,kc) — in flight for a full chunk-compute —
            // and guarantees everyone is done reading the other buffer.
            __syncthreads();

            // issue next-stage DMA into the other buffer (hidden under compute)
            {
                int kc2 = kc + KC, jt2 = jt;
                if (kc2 == K_DIM) { kc2 = 0; jt2 += JT; }
                if (jt2 < JLEN) {
                    const float* gb = embT + (size_t)kc2 * EMB_LEN + jbase + jt2 + l4;
                    float* lb = &es[buf ^ 1][w][0];
                    dma16(gb + (size_t)(0 + w) * EMB_LEN, lb + 0 * JT);
                    dma16(gb + (size_t)(4 + w) * EMB_LEN, lb + 4 * JT);
                    dma16(gb + (size_t)(8 + w) * EMB_LEN, lb + 8 * JT);
                    dma16(gb + (size_t)(12 + w) * EMB_LEN, lb + 12 * JT);
                }
            }

            const float (*eb)[JT] = es[buf];
#pragma unroll
            for (int g = 0; g < 4; ++g) {
                // a-operand for 8 rows x 4 k's: explicit SMEM batch.
                // Row stride = K_DIM*4 = 0x200 bytes (literal offsets);
                // base = this group's k offset (wave-uniform -> SGPR pair).
                u32x4 A0, A1, A2, A3, A4, A5, A6, A7;
                unsigned long long base =
                    zb + (unsigned long long)((kc + g * 4) * 4);
                asm volatile(
                    "s_load_dwordx4 %0, %8, 0x0\n\t"
                    "s_load_dwordx4 %1, %8, 0x200\n\t"
                    "s_load_dwordx4 %2, %8, 0x400\n\t"
                    "s_load_dwordx4 %3, %8, 0x600\n\t"
                    "s_load_dwordx4 %4, %8, 0x800\n\t"
                    "s_load_dwordx4 %5, %8, 0xa00\n\t"
                    "s_load_dwordx4 %6, %8, 0xc00\n\t"
                    "s_load_dwordx4 %7, %8, 0xe00\n\t"
                    "s_waitcnt lgkmcnt(0)"
                    : "=&s"(A0), "=&s"(A1), "=&s"(A2), "=&s"(A3),
                      "=&s"(A4), "=&s"(A5), "=&s"(A6), "=&s"(A7)
                    : "s"(base));
                KSTEP(g, 0)
                KSTEP(g, 1)
                KSTEP(g, 2)
                KSTEP(g, 3)
            }
            buf ^= 1;
        }

        // per-jt epilogue: d = C - 2g; ascending-j strict-< running best
        int jb = jbase + jt + l4;
        UPD(0, c0)
        UPD(1, c1)
        UPD(2, c2)
        UPD(3, c3)
        UPD(4, c4)
        UPD(5, c5)
        UPD(6, c6)
        UPD(7, c7)
    }

    // final cross-lane lexicographic (d,j) reduce per row; lane 0 writes
    RED(0)
    RED(1)
    RED(2)
    RED(3)
    RED(4)
    RED(5)
    RED(6)
    RED(7)
}

// ---------------------------------------------------------------------------
// Kernel 3: merge splits (ascending split + strict < => smallest j wins ties)
// ---------------------------------------------------------------------------
__global__ void merge_kernel(const float* __restrict__ cand_d,
                             const int* __restrict__ cand_j,
                             int* __restrict__ idxw,
                             float* __restrict__ out_idx) {
    int b = blockIdx.x * 256 + threadIdx.x;
    float bd = cand_d[b];
    int bj = cand_j[b];
#pragma unroll
    for (int s = 1; s < JSPLIT; ++s) {
        float d = cand_d[s * B_ROWS + b];
        int j = cand_j[s * B_ROWS + b];
        if (d < bd) { bd = d; bj = j; }
    }
    idxw[b] = bj;
    out_idx[b] = (float)bj;
}

// ---------------------------------------------------------------------------
// Kernel 4: z_q_out (transposed) + moment sums for loss
// ---------------------------------------------------------------------------
__global__ void output_kernel(const float* __restrict__ z,
                              const float* __restrict__ emb,
                              const int* __restrict__ idxw,
                              float* __restrict__ out,
                              double* __restrict__ accs) {
    int stride = gridDim.x * blockDim.x;
    double s[6] = {0, 0, 0, 0, 0, 0};
    for (int n = blockIdx.x * blockDim.x + threadIdx.x; n < B_ROWS * 128; n += stride) {
        int b = n >> 7, i = n & 127;
        int c = i >> 3, h = (i >> 2) & 1, w = i & 3;   // i = c*8 + h*4 + w
        float zv = z[n];
        float qv = emb[(size_t)idxw[b] * 128 + i];
        float diff = qv - zv;                          // z_q - z (fp32, as ref)
        out[(size_t)((b * 4 + w) * 16 + c) * 2 + h] = zv + diff;
        s[0] += (double)qv;
        s[1] += (double)zv;
        s[2] += (double)qv * qv;
        s[3] += (double)zv * zv;
        s[4] += (double)qv * zv;
        s[5] += (double)diff * diff;
    }
    int lane = threadIdx.x & 63, wv = threadIdx.x >> 6;
#pragma unroll
    for (int q = 0; q < 6; ++q)
        for (int o = 32; o; o >>= 1) s[q] += __shfl_down(s[q], o, 64);
    __shared__ double sm[6][4];
    if (lane == 0)
#pragma unroll
        for (int q = 0; q < 6; ++q) sm[q][wv] = s[q];
    __syncthreads();
    if (threadIdx.x == 0) {
#pragma unroll
        for (int q = 0; q < 6; ++q)
            atomicAdd(&accs[q], sm[q][0] + sm[q][1] + sm[q][2] + sm[q][3]);
    }
}

// ---------------------------------------------------------------------------
// Kernel 5: per-column L1 of emb (for reg term)
// ---------------------------------------------------------------------------
__global__ void colsum_kernel(const float* __restrict__ emb, float* __restrict__ colsum) {
    int j = blockIdx.x;   // 0..127
    double s = 0;
    for (int i = threadIdx.x; i < EMB_LEN; i += blockDim.x)
        s += (double)fabsf(emb[(size_t)i * 128 + j]);
    int lane = threadIdx.x & 63, wv = threadIdx.x >> 6;
    for (int o = 32; o; o >>= 1) s += __shfl_down(s, o, 64);
    __shared__ double sm[4];
    if (lane == 0) sm[wv] = s;
    __syncthreads();
    if (threadIdx.x == 0) colsum[j] = (float)(sm[0] + sm[1] + sm[2] + sm[3]);
}

// ---------------------------------------------------------------------------
// Kernel 6: final loss
// ---------------------------------------------------------------------------
__global__ void loss_kernel(const double* __restrict__ accs,
                            const float* __restrict__ colsum,
                            float* __restrict__ out_loss) {
    __shared__ float sm[128];
    int tid = threadIdx.x;
    sm[tid] = colsum[tid];
    __syncthreads();
    for (int s = 64; s; s >>= 1) {
        if (tid < s) sm[tid] = fmaxf(sm[tid], sm[tid + s]);
        __syncthreads();
    }
    if (tid == 0) {
        double n = (double)B_ROWS * 128.0;
        double m = accs[5] / n;                   // mean((z_q - z)^2)
        double commit = 0.25 * m + m;
        double Sx = accs[0], Sy = accs[1], Sxx = accs[2], Syy = accs[3], Sxy = accs[4];
        double cov = Sxy - Sx * Sy / n;
        double vx = Sxx - Sx * Sx / n;
        double vy = Syy - Sy * Sy / n;
        double pearson = 0.5 + 0.5 * cov / (sqrt(vx) * sqrt(vy));
        double reg = 0.01 * (double)sm[0];
        out_loss[0] = (float)(commit + pearson + reg);
    }
}

// ---------------------------------------------------------------------------
extern "C" void kernel_launch(void* const* d_in, const int* in_sizes, int n_in,
                              void* d_out, int out_size, void* d_ws, size_t ws_size,
                              hipStream_t stream) {
    const float* z = (const float*)d_in[0];      // 16384*16*2*4
    const float* emb = (const float*)d_in[1];    // 16384*128
    float* out = (float*)d_out;                  // 2097152 (z_q_out) + 1 (loss) + 16384 (idx)

    float* zf = (float*)d_ws;                    // 2097152 floats
    float* embT = zf + 2097152;                  // 2097152 floats (emb transposed)
    float* Cb = embT + 2097152;                  // 16384
    float* cand_d = Cb + 16384;                  // JSPLIT*16384
    int* cand_j = (int*)(cand_d + JSPLIT * B_ROWS);
    int* idxw = cand_j + JSPLIT * B_ROWS;        // 16384
    double* accs = (double*)(idxw + 16384);      // 8 doubles
    float* colsum = (float*)(accs + 8);          // 128

    hipMemsetAsync(accs, 0, 8 * sizeof(double), stream);

    zf_kernel<<<B_ROWS, 128, 0, stream>>>(z, zf, Cb);
    transpose_kernel<<<EMB_LEN / 64, 256, 0, stream>>>(emb, embT);
    argmin_kernel<<<512 * JSPLIT, 256, 0, stream>>>(zf, Cb, embT, cand_d, cand_j);
    merge_kernel<<<B_ROWS / 256, 256, 0, stream>>>(cand_d, cand_j, idxw, out + 2097153);
    output_kernel<<<1024, 256, 0, stream>>>(z, emb, idxw, out, accs);
    colsum_kernel<<<128, 256, 0, stream>>>(emb, colsum);
    loss_kernel<<<1, 128, 0, stream>>>(accs, colsum, out + 2097152);
}

// Round 8
// 910.449 us; speedup vs baseline: 2.4722x; 1.0016x over previous
//
#include <hip/hip_runtime.h>
#include <cstdint>
#include <cstddef>

#define B_ROWS 16384
#define EMB_LEN 16384
#define K_DIM 128
#define JSPLIT 8
#define JLEN (EMB_LEN / JSPLIT)   // 2048
#define RB 32                     // rows per block
#define JT 256                    // j-tile (4 j per lane — proven width)
#define KC 8                      // k chunk (R13: 16 -> 8; LDS 32 KB -> 16 KB -> 8 blocks/CU)

typedef const __attribute__((address_space(1))) void* gas_vp;
typedef __attribute__((address_space(3))) void* las_vp;
typedef __attribute__((ext_vector_type(4))) unsigned int u32x4;

__device__ __forceinline__ void dma16(const float* g, float* l) {
    // global -> LDS direct copy, 16 B/lane; LDS dest = wave-uniform base + lane*16
    __builtin_amdgcn_global_load_lds((gas_vp)g, (las_vp)l, 16, 0, 0);
}

// wave-uniform float -> SGPR (bit-identical value)
__device__ __forceinline__ float rfl(float x) {
    return __int_as_float(__builtin_amdgcn_readfirstlane(__float_as_int(x)));
}

// ---------------------------------------------------------------------------
// Kernel 1: zf + C per row.  (frozen — absmax 0 throughout)
// ---------------------------------------------------------------------------
__global__ void zf_kernel(const float* __restrict__ z,
                          float* __restrict__ zf, float* __restrict__ Cb) {
    int b = blockIdx.x;
    int i = threadIdx.x;                 // 0..127
    int c = i >> 3, h = (i >> 1) & 1, wp = i & 1;
    const float* zr = z + (size_t)b * 128 + c * 8 + h * 4 + wp * 2;
    float v = 0.5f * zr[0] + 0.5f * zr[1];
    zf[(size_t)b * 128 + i] = v;
    float s = v * v;
    for (int o = 32; o; o >>= 1) s += __shfl_down(s, o, 64);
    __shared__ float sm[2];
    if ((threadIdx.x & 63) == 0) sm[threadIdx.x >> 6] = s;
    __syncthreads();
    if (threadIdx.x == 0) Cb[b] = sm[0] + sm[1];
}

// ---------------------------------------------------------------------------
// Kernel 1b: embT[k][j] = emb[j][k]  (frozen — verified R4+)
// ---------------------------------------------------------------------------
__global__ void transpose_kernel(const float* __restrict__ emb,
                                 float* __restrict__ embT) {
    __shared__ float t[128][65];   // [k][j-local], +1 pad
    int j0 = blockIdx.x * 64;
    int jl = threadIdx.x >> 2;         // 0..63
    int kq = threadIdx.x & 3;          // 0..3
    const float* er = emb + (size_t)(j0 + jl) * 128;
#pragma unroll
    for (int q = 0; q < 8; ++q) {
        int k4 = (kq * 8 + q) * 4;
        float4 v = *(const float4*)(er + k4);
        t[k4 + 0][jl] = v.x;
        t[k4 + 1][jl] = v.y;
        t[k4 + 2][jl] = v.z;
        t[k4 + 3][jl] = v.w;
    }
    __syncthreads();
    int kk = threadIdx.x >> 4;         // 0..15
    int jl4 = (threadIdx.x & 15) * 4;
#pragma unroll
    for (int q = 0; q < 8; ++q) {
        int k = kk + q * 16;
        float4 v = make_float4(t[k][jl4], t[k][jl4 + 1], t[k][jl4 + 2], t[k][jl4 + 3]);
        *(float4*)(embT + (size_t)k * EMB_LEN + j0 + jl4) = v;
    }
}

// ---------------------------------------------------------------------------
// Kernel 2: argmin of d = C - 2*dot(zf, e_j).
// R13 = R12 (s_load a-operand on SMEM pipe, 4-wide j, es-only LDS, DMA
// double-buffer, named bd/bj, VGPR 48 no-spill) with KC 16 -> 8.
// R12 POST-MORTEM: scalar-pipe port verified (SGPR 112, spill gone, 1
// ds_read/k-step) but only 866->813 us: the remaining 22% VALU-idle is the
// per-group `s_waitcnt lgkmcnt(0)` SMEM drain (SMEM returns out-of-order ->
// counted waits unsafe; full drain every 4 k-steps) at only ~3.4 waves/SIMD
// of TLP (occupancy LDS-capped: 32 KB/block -> ~4 blocks/CU).
// FIX: halve the staged chunk.  LDS 16 KB/block -> 8 blocks/CU (32-wave cap)
// = 8 waves/SIMD: SMEM drains + barriers now overlap across ~8 resident
// blocks.  Inter-barrier window stays 8 k-steps (~512 issue-cyc) >> L2
// latency for the 2-DMA/thread stage.
// Arithmetic contract (frozen, absmax 0 throughout): per (r,j) single fp32
// FMA chain ascending k (identical zf bits, identical order); d = C - 2g;
// strict < argmin ascending j; lexicographic (d,j) wave reduce; splits
// ascending.
// ---------------------------------------------------------------------------
#define FMA_ROW(cr, av) \
    cr.x = fmaf(av, bv.x, cr.x); \
    cr.y = fmaf(av, bv.y, cr.y); \
    cr.z = fmaf(av, bv.z, cr.z); \
    cr.w = fmaf(av, bv.w, cr.w);

// one k-step: bv from LDS (per-lane), a-values from SGPRs (kk is a literal)
#define KSTEP(g, kk) { \
    const float4 bv = *(const float4*)(&eb[(g) * 4 + (kk)][l4]); \
    FMA_ROW(c0, __uint_as_float(A0[kk])) \
    FMA_ROW(c1, __uint_as_float(A1[kk])) \
    FMA_ROW(c2, __uint_as_float(A2[kk])) \
    FMA_ROW(c3, __uint_as_float(A3[kk])) \
    FMA_ROW(c4, __uint_as_float(A4[kk])) \
    FMA_ROW(c5, __uint_as_float(A5[kk])) \
    FMA_ROW(c6, __uint_as_float(A6[kk])) \
    FMA_ROW(c7, __uint_as_float(A7[kk])) \
}

// 8 rows x 4 k scalar batch (row stride 0x200 B) + full drain inside the block
#define ALOAD(g) \
    u32x4 A0, A1, A2, A3, A4, A5, A6, A7; \
    { \
        unsigned long long base = zb + (unsigned long long)((kc + (g) * 4) * 4); \
        asm volatile( \
            "s_load_dwordx4 %0, %8, 0x0\n\t" \
            "s_load_dwordx4 %1, %8, 0x200\n\t" \
            "s_load_dwordx4 %2, %8, 0x400\n\t" \
            "s_load_dwordx4 %3, %8, 0x600\n\t" \
            "s_load_dwordx4 %4, %8, 0x800\n\t" \
            "s_load_dwordx4 %5, %8, 0xa00\n\t" \
            "s_load_dwordx4 %6, %8, 0xc00\n\t" \
            "s_load_dwordx4 %7, %8, 0xe00\n\t" \
            "s_waitcnt lgkmcnt(0)" \
            : "=&s"(A0), "=&s"(A1), "=&s"(A2), "=&s"(A3), \
              "=&s"(A4), "=&s"(A5), "=&s"(A6), "=&s"(A7) \
            : "s"(base)); \
    }

// ascending-j strict-< running chain (earliest j wins ties == lexicographic min)
#define UPD(rr, cr) { \
    float dv0 = cb##rr - 2.0f * cr.x; \
    float dv1 = cb##rr - 2.0f * cr.y; \
    float dv2 = cb##rr - 2.0f * cr.z; \
    float dv3 = cb##rr - 2.0f * cr.w; \
    if (dv0 < bd##rr) { bd##rr = dv0; bj##rr = jb; } \
    if (dv1 < bd##rr) { bd##rr = dv1; bj##rr = jb + 1; } \
    if (dv2 < bd##rr) { bd##rr = dv2; bj##rr = jb + 2; } \
    if (dv3 < bd##rr) { bd##rr = dv3; bj##rr = jb + 3; } \
}

#define RED(rr) { \
    float bd = bd##rr; int bj = bj##rr; \
    for (int o = 32; o; o >>= 1) { \
        float d2 = __shfl_down(bd, o, 64); \
        int j2 = __shfl_down(bj, o, 64); \
        if (d2 < bd || (d2 == bd && j2 < bj)) { bd = d2; bj = j2; } \
    } \
    if (l == 0) { \
        cand_d[sp * B_ROWS + rbase + w8 + rr] = bd; \
        cand_j[sp * B_ROWS + rbase + w8 + rr] = bj; \
    } \
}

__global__ void argmin_kernel(const float* __restrict__ zf,
                              const float* __restrict__ Cb,
                              const float* __restrict__ embT,
                              float* __restrict__ cand_d,
                              int* __restrict__ cand_j) {
    __shared__ float es[2][KC][JT];    // double-buffered staged chunk, 16 KB (only LDS)

    int sp = blockIdx.x & 7;           // XCD id under round-robin dispatch
    int rb = blockIdx.x >> 3;          // 0..511
    int rbase = rb * RB;
    int jbase = sp * JLEN;
    int tid = threadIdx.x;
    int w = tid >> 6;                  // wave 0..3
    int l = tid & 63;
    int w8 = w << 3;
    int l4 = l << 2;

    // wave-uniform row base -> scalar (SGPR) address of this wave's 8 zf rows
    int rbu = __builtin_amdgcn_readfirstlane(rbase + w8);
    unsigned long long zb =
        (unsigned long long)(uintptr_t)zf + (unsigned long long)rbu * (K_DIM * 4);

    // row constants — wave-uniform, pinned to SGPR (proven R10/R12 path)
    const float* cbp = Cb + rbu;
    float cb0 = rfl(cbp[0]), cb1 = rfl(cbp[1]), cb2 = rfl(cbp[2]), cb3 = rfl(cbp[3]);
    float cb4 = rfl(cbp[4]), cb5 = rfl(cbp[5]), cb6 = rfl(cbp[6]), cb7 = rfl(cbp[7]);

    // per-lane running best (named scalars)
    float bd0 = 3.4e38f, bd1 = 3.4e38f, bd2 = 3.4e38f, bd3 = 3.4e38f;
    float bd4 = 3.4e38f, bd5 = 3.4e38f, bd6 = 3.4e38f, bd7 = 3.4e38f;
    int bj0 = 0, bj1 = 0, bj2 = 0, bj3 = 0, bj4 = 0, bj5 = 0, bj6 = 0, bj7 = 0;

    // prologue DMA: stage (jt=0, kc=0) into buffer 0
    // wave w stages k-rows {w, w+4}; each dma16 covers one k-row (256 floats)
    {
        const float* gb = embT + jbase + l4;
        dma16(gb + (size_t)(0 + w) * EMB_LEN, &es[0][0 + w][0]);
        dma16(gb + (size_t)(4 + w) * EMB_LEN, &es[0][4 + w][0]);
    }

    int buf = 0;
    for (int jt = 0; jt < JLEN; jt += JT) {
        float4 c0 = make_float4(0.f, 0.f, 0.f, 0.f);
        float4 c1 = make_float4(0.f, 0.f, 0.f, 0.f);
        float4 c2 = make_float4(0.f, 0.f, 0.f, 0.f);
        float4 c3 = make_float4(0.f, 0.f, 0.f, 0.f);
        float4 c4 = make_float4(0.f, 0.f, 0.f, 0.f);
        float4 c5 = make_float4(0.f, 0.f, 0.f, 0.f);
        float4 c6 = make_float4(0.f, 0.f, 0.f, 0.f);
        float4 c7 = make_float4(0.f, 0.f, 0.f, 0.f);

        for (int kc = 0; kc < K_DIM; kc += KC) {
            // Drains the DMA for (jt,kc) — in flight for a full chunk-compute —
            // and guarantees everyone is done reading the other buffer.
            __syncthreads();

            // issue next-stage DMA into the other buffer (hidden under compute)
            {
                int kc2 = kc + KC, jt2 = jt;
                if (kc2 == K_DIM) { kc2 = 0; jt2 += JT; }
                if (jt2 < JLEN) {
                    const float* gb = embT + (size_t)kc2 * EMB_LEN + jbase + jt2 + l4;
                    dma16(gb + (size_t)(0 + w) * EMB_LEN, &es[buf ^ 1][0 + w][0]);
                    dma16(gb + (size_t)(4 + w) * EMB_LEN, &es[buf ^ 1][4 + w][0]);
                }
            }

            const float (*eb)[JT] = es[buf];
            {
                ALOAD(0)
                KSTEP(0, 0)
                KSTEP(0, 1)
                KSTEP(0, 2)
                KSTEP(0, 3)
            }
            {
                ALOAD(1)
                KSTEP(1, 0)
                KSTEP(1, 1)
                KSTEP(1, 2)
                KSTEP(1, 3)
            }
            buf ^= 1;
        }

        // per-jt epilogue: d = C - 2g; ascending-j strict-< running best
        int jb = jbase + jt + l4;
        UPD(0, c0)
        UPD(1, c1)
        UPD(2, c2)
        UPD(3, c3)
        UPD(4, c4)
        UPD(5, c5)
        UPD(6, c6)
        UPD(7, c7)
    }

    // final cross-lane lexicographic (d,j) reduce per row; lane 0 writes
    RED(0)
    RED(1)
    RED(2)
    RED(3)
    RED(4)
    RED(5)
    RED(6)
    RED(7)
}

// ---------------------------------------------------------------------------
// Kernel 3: merge splits (ascending split + strict < => smallest j wins ties)
// ---------------------------------------------------------------------------
__global__ void merge_kernel(const float* __restrict__ cand_d,
                             const int* __restrict__ cand_j,
                             int* __restrict__ idxw,
                             float* __restrict__ out_idx) {
    int b = blockIdx.x * 256 + threadIdx.x;
    float bd = cand_d[b];
    int bj = cand_j[b];
#pragma unroll
    for (int s = 1; s < JSPLIT; ++s) {
        float d = cand_d[s * B_ROWS + b];
        int j = cand_j[s * B_ROWS + b];
        if (d < bd) { bd = d; bj = j; }
    }
    idxw[b] = bj;
    out_idx[b] = (float)bj;
}

// ---------------------------------------------------------------------------
// Kernel 4: z_q_out (transposed) + moment sums for loss
// ---------------------------------------------------------------------------
__global__ void output_kernel(const float* __restrict__ z,
                              const float* __restrict__ emb,
                              const int* __restrict__ idxw,
                              float* __restrict__ out,
                              double* __restrict__ accs) {
    int stride = gridDim.x * blockDim.x;
    double s[6] = {0, 0, 0, 0, 0, 0};
    for (int n = blockIdx.x * blockDim.x + threadIdx.x; n < B_ROWS * 128; n += stride) {
        int b = n >> 7, i = n & 127;
        int c = i >> 3, h = (i >> 2) & 1, w = i & 3;   // i = c*8 + h*4 + w
        float zv = z[n];
        float qv = emb[(size_t)idxw[b] * 128 + i];
        float diff = qv - zv;                          // z_q - z (fp32, as ref)
        out[(size_t)((b * 4 + w) * 16 + c) * 2 + h] = zv + diff;
        s[0] += (double)qv;
        s[1] += (double)zv;
        s[2] += (double)qv * qv;
        s[3] += (double)zv * zv;
        s[4] += (double)qv * zv;
        s[5] += (double)diff * diff;
    }
    int lane = threadIdx.x & 63, wv = threadIdx.x >> 6;
#pragma unroll
    for (int q = 0; q < 6; ++q)
        for (int o = 32; o; o >>= 1) s[q] += __shfl_down(s[q], o, 64);
    __shared__ double sm[6][4];
    if (lane == 0)
#pragma unroll
        for (int q = 0; q < 6; ++q) sm[q][wv] = s[q];
    __syncthreads();
    if (threadIdx.x == 0) {
#pragma unroll
        for (int q = 0; q < 6; ++q)
            atomicAdd(&accs[q], sm[q][0] + sm[q][1] + sm[q][2] + sm[q][3]);
    }
}

// ---------------------------------------------------------------------------
// Kernel 5: per-column L1 of emb (for reg term)
// ---------------------------------------------------------------------------
__global__ void colsum_kernel(const float* __restrict__ emb, float* __restrict__ colsum) {
    int j = blockIdx.x;   // 0..127
    double s = 0;
    for (int i = threadIdx.x; i < EMB_LEN; i += blockDim.x)
        s += (double)fabsf(emb[(size_t)i * 128 + j]);
    int lane = threadIdx.x & 63, wv = threadIdx.x >> 6;
    for (int o = 32; o; o >>= 1) s += __shfl_down(s, o, 64);
    __shared__ double sm[4];
    if (lane == 0) sm[wv] = s;
    __syncthreads();
    if (threadIdx.x == 0) colsum[j] = (float)(sm[0] + sm[1] + sm[2] + sm[3]);
}

// ---------------------------------------------------------------------------
// Kernel 6: final loss
// ---------------------------------------------------------------------------
__global__ void loss_kernel(const double* __restrict__ accs,
                            const float* __restrict__ colsum,
                            float* __restrict__ out_loss) {
    __shared__ float sm[128];
    int tid = threadIdx.x;
    sm[tid] = colsum[tid];
    __syncthreads();
    for (int s = 64; s; s >>= 1) {
        if (tid < s) sm[tid] = fmaxf(sm[tid], sm[tid + s]);
        __syncthreads();
    }
    if (tid == 0) {
        double n = (double)B_ROWS * 128.0;
        double m = accs[5] / n;                   // mean((z_q - z)^2)
        double commit = 0.25 * m + m;
        double Sx = accs[0], Sy = accs[1], Sxx = accs[2], Syy = accs[3], Sxy = accs[4];
        double cov = Sxy - Sx * Sy / n;
        double vx = Sxx - Sx * Sx / n;
        double vy = Syy - Sy * Sy / n;
        double pearson = 0.5 + 0.5 * cov / (sqrt(vx) * sqrt(vy));
        double reg = 0.01 * (double)sm[0];
        out_loss[0] = (float)(commit + pearson + reg);
    }
}

// ---------------------------------------------------------------------------
extern "C" void kernel_launch(void* const* d_in, const int* in_sizes, int n_in,
                              void* d_out, int out_size, void* d_ws, size_t ws_size,
                              hipStream_t stream) {
    const float* z = (const float*)d_in[0];      // 16384*16*2*4
    const float* emb = (const float*)d_in[1];    // 16384*128
    float* out = (float*)d_out;                  // 2097152 (z_q_out) + 1 (loss) + 16384 (idx)

    float* zf = (float*)d_ws;                    // 2097152 floats
    float* embT = zf + 2097152;                  // 2097152 floats (emb transposed)
    float* Cb = embT + 2097152;                  // 16384
    float* cand_d = Cb + 16384;                  // JSPLIT*16384
    int* cand_j = (int*)(cand_d + JSPLIT * B_ROWS);
    int* idxw = cand_j + JSPLIT * B_ROWS;        // 16384
    double* accs = (double*)(idxw + 16384);      // 8 doubles
    float* colsum = (float*)(accs + 8);          // 128

    hipMemsetAsync(accs, 0, 8 * sizeof(double), stream);

    zf_kernel<<<B_ROWS, 128, 0, stream>>>(z, zf, Cb);
    transpose_kernel<<<EMB_LEN / 64, 256, 0, stream>>>(emb, embT);
    argmin_kernel<<<512 * JSPLIT, 256, 0, stream>>>(zf, Cb, embT, cand_d, cand_j);
    merge_kernel<<<B_ROWS / 256, 256, 0, stream>>>(cand_d, cand_j, idxw, out + 2097153);
    output_kernel<<<1024, 256, 0, stream>>>(z, emb, idxw, out, accs);
    colsum_kernel<<<128, 256, 0, stream>>>(emb, colsum);
    loss_kernel<<<1, 128, 0, stream>>>(accs, colsum, out + 2097152);
}